// Round 3
// baseline (4260.581 us; speedup 1.0000x reference)
//
#include <hip/hip_runtime.h>
#include <cstdint>
#include <cstddef>

#define B_    256
#define Q_    512
#define D_    32
#define H_    192
#define HID_  384
#define INCH_ 96
#define M_    (B_*Q_)    // 131072
#define WOUT_ 64
#define BPB   2          // batches per rollout block
#define RT_   768        // rollout threads: 4 quarters x 192, 12 waves
#define PI_F  3.14159265358979323846f

typedef unsigned int uint_t;

__device__ __forceinline__ float sigm(float x){ return 1.f/(1.f+expf(-x)); }
__device__ __forceinline__ float gelu_exact(float x){ return 0.5f*x*(1.f+erff(x*0.7071067811865475f)); }

// ---------------- features: [x, dy, ddy] ----------------
__global__ void feats_kernel(const float* __restrict__ x, float* __restrict__ feats, int nrows){
  int idx = blockIdx.x*256 + threadIdx.x;
  if (idx >= nrows*32) return;
  int d  = idx & 31;
  int bt = idx >> 5;
  int t  = bt & 511;
  const float* xr = x + (size_t)bt*D_;
  float xc  = xr[d];
  float xm1 = (t>0) ? xr[d - D_]   : 0.f;
  float xm2 = (t>1) ? xr[d - 2*D_] : 0.f;
  float dy   = (t>0) ? xc - xm1   : 0.f;
  float dym1 = (t>1) ? xm1 - xm2  : 0.f;
  float ddy  = (t>0) ? dy - dym1  : 0.f;
  float* fr = feats + (size_t)bt*INCH_;
  fr[d] = xc; fr[D_+d] = dy; fr[2*D_+d] = ddy;
}

// ---------------- 64x64x8 fp32 tiled GEMM, 4 blocks/CU ----------------
// MODE 0: out = acc+bias ; MODE 1: out = gelu(acc+bias) ; MODE 2: A affine, C += acc+bias
template<int MODE>
__global__ __launch_bounds__(256,4) void gemm_t64(
    const float* __restrict__ Af,
    const float* __restrict__ W,  const float* __restrict__ bias,
    float* __restrict__ Cf,
    const float* __restrict__ scale, const float* __restrict__ grnb,
    int N, int K)
{
  __shared__ float As[8][64];
  __shared__ float Bs[8][64];
  const int tid = threadIdx.x;
  const int bm = blockIdx.x*64, bn = blockIdx.y*64;
  const int tx = tid & 15, ty = tid >> 4;
  const int lrow = (tid & 127) >> 1, lk = (tid & 1)*4;
  const bool isA = tid < 128;
  const float* srow = (MODE==2) ? (scale + (size_t)(bm>>9)*HID_) : nullptr;

  float acc[4][4];
  #pragma unroll
  for (int i=0;i<4;i++)
    #pragma unroll
    for (int j=0;j<4;j++) acc[i][j]=0.f;

  const float* gsrc = isA ? (Af + (size_t)(bm+lrow)*K) : (W + (size_t)(bn+lrow)*K);

  for (int k0=0;k0<K;k0+=8){
    float4 v = *(const float4*)(gsrc + k0 + lk);
    if (MODE==2 && isA){
      int c = k0+lk;
      float4 sc = *(const float4*)(srow+c);
      float4 gb = *(const float4*)(grnb+c);
      v.x = v.x*sc.x+gb.x; v.y = v.y*sc.y+gb.y;
      v.z = v.z*sc.z+gb.z; v.w = v.w*sc.w+gb.w;
    }
    if (isA){
      As[lk+0][lrow]=v.x; As[lk+1][lrow]=v.y; As[lk+2][lrow]=v.z; As[lk+3][lrow]=v.w;
    } else {
      Bs[lk+0][lrow]=v.x; Bs[lk+1][lrow]=v.y; Bs[lk+2][lrow]=v.z; Bs[lk+3][lrow]=v.w;
    }
    __syncthreads();
    #pragma unroll
    for (int kk=0;kk<8;kk++){
      float4 a = *(const float4*)&As[kk][ty*4];
      float4 b = *(const float4*)&Bs[kk][tx*4];
      float ar[4] = {a.x,a.y,a.z,a.w};
      #pragma unroll
      for (int i=0;i<4;i++){
        acc[i][0] += ar[i]*b.x; acc[i][1] += ar[i]*b.y;
        acc[i][2] += ar[i]*b.z; acc[i][3] += ar[i]*b.w;
      }
    }
    __syncthreads();
  }

  const int o0 = bn + tx*4;
  float4 b0 = *(const float4*)(bias + o0);
  #pragma unroll
  for (int i=0;i<4;i++){
    int m = bm + ty*4 + i;
    if (MODE==0){
      float4 v; v.x=acc[i][0]+b0.x; v.y=acc[i][1]+b0.y; v.z=acc[i][2]+b0.z; v.w=acc[i][3]+b0.w;
      *(float4*)(Cf + (size_t)m*N + o0) = v;
    } else if (MODE==1){
      float4 v;
      v.x = gelu_exact(acc[i][0]+b0.x); v.y = gelu_exact(acc[i][1]+b0.y);
      v.z = gelu_exact(acc[i][2]+b0.z); v.w = gelu_exact(acc[i][3]+b0.w);
      *(float4*)(Cf + (size_t)m*N + o0) = v;
    } else {
      float4 old = *(const float4*)(Cf + (size_t)m*N + o0);
      float4 v; v.x=old.x+acc[i][0]+b0.x; v.y=old.y+acc[i][1]+b0.y;
      v.z=old.z+acc[i][2]+b0.z; v.w=old.w+acc[i][3]+b0.w;
      *(float4*)(Cf + (size_t)m*N + o0) = v;
    }
  }
}

// ---------------- depthwise conv (k=9, edge pad) + LN, 4 timesteps per block ----------------
__global__ __launch_bounds__(192) void dwconv_ln4(
  const float* __restrict__ h, const float* __restrict__ dww, const float* __restrict__ dwb,
  const float* __restrict__ lnw, const float* __restrict__ lnb, float* __restrict__ yln)
{
  __shared__ float sh[12][192];
  __shared__ float rs_[192], rq_[192], st[2];
  const int c  = threadIdx.x;
  const int t0 = (blockIdx.x & 127) * 4;
  const size_t base = (size_t)(blockIdx.x >> 7) * Q_ * H_;
  #pragma unroll
  for (int r=0;r<12;r++){
    int tt = t0 - 4 + r; tt = tt<0?0:(tt>511?511:tt);
    sh[r][c] = h[base + (size_t)tt*H_ + c];
  }
  float w[9];
  #pragma unroll
  for (int k=0;k<9;k++) w[k] = dww[c*9+k];
  const float dbias = dwb[c], lw = lnw[c], lb = lnb[c];
  __syncthreads();
  for (int i=0;i<4;i++){
    float acc = dbias;
    #pragma unroll
    for (int k=0;k<9;k++) acc += w[k]*sh[i+k][c];
    rs_[c]=acc; rq_[c]=acc*acc;
    __syncthreads();
    if (c < 64){
      float s = rs_[c]+rs_[c+64]+rs_[c+128];
      float q = rq_[c]+rq_[c+64]+rq_[c+128];
      #pragma unroll
      for (int off=32; off>0; off>>=1){ s += __shfl_down(s,off); q += __shfl_down(q,off); }
      if (c==0){ st[0]=s; st[1]=q; }
    }
    __syncthreads();
    float mean = st[0]*(1.f/H_);
    float var  = st[1]*(1.f/H_) - mean*mean;
    float r = rsqrtf(var + 1e-5f);
    yln[base + (size_t)(t0+i)*H_ + c] = (acc-mean)*r*lw + lb;
  }
}

// ---------------- output LayerNorm (+ save last-timestep row) ----------------
__global__ __launch_bounds__(192) void out_ln_kernel(
  const float* __restrict__ h, const float* __restrict__ lnw, const float* __restrict__ lnb,
  float* __restrict__ o, float* __restrict__ hlast, int b0)
{
  __shared__ float rs_[192], rq_[192], st[2];
  const int c  = threadIdx.x;
  const int bt = blockIdx.x;
  float v = h[(size_t)bt*H_ + c];
  rs_[c]=v; rq_[c]=v*v;
  __syncthreads();
  if (c < 64){
    float s = rs_[c]+rs_[c+64]+rs_[c+128];
    float q = rq_[c]+rq_[c+64]+rq_[c+128];
    #pragma unroll
    for (int off=32; off>0; off>>=1){ s += __shfl_down(s,off); q += __shfl_down(q,off); }
    if (c==0){ st[0]=s; st[1]=q; }
  }
  __syncthreads();
  float mean = st[0]*(1.f/H_);
  float var  = st[1]*(1.f/H_) - mean*mean;
  float r = rsqrtf(var + 1e-5f);
  float res = (v-mean)*r*lnw[c] + lnb[c];
  o[(size_t)bt*H_ + c] = res;
  if ((bt & 511) == 511) hlast[(size_t)(b0 + (bt>>9))*H_ + c] = res;
}

// ---------------- GRN stats ----------------
__global__ __launch_bounds__(384) void grn_stats_kernel(
  const float* __restrict__ y1, const float* __restrict__ grn_g, float* __restrict__ scale)
{
  __shared__ float r[384];
  const int c = threadIdx.x;
  const int b = blockIdx.x;
  const float* p = y1 + (size_t)b*Q_*HID_ + c;
  float s = 0.f;
  #pragma unroll 8
  for (int t=0;t<Q_;t++){ float v = p[(size_t)t*HID_]; s += v*v; }
  float gx = sqrtf(s);
  r[c] = gx;
  __syncthreads();
  if (c < 64){
    float v = r[c]+r[c+64]+r[c+128]+r[c+192]+r[c+256]+r[c+320];
    #pragma unroll
    for (int off=32; off>0; off>>=1) v += __shfl_down(v,off);
    if (c==0) r[0]=v;
  }
  __syncthreads();
  float mean = r[0]*(1.f/HID_);
  scale[(size_t)b*HID_ + c] = 1.f + grn_g[c]*gx/(mean + 1e-6f);
}

// ---------------- pack fc_rp / fc_gain into padded (64,192) W ----------------
__global__ void pack_w_kernel(const float* __restrict__ frw, const float* __restrict__ frb,
                              const float* __restrict__ fgw, const float* __restrict__ fgb,
                              float* __restrict__ w_pad, float* __restrict__ b_pad)
{
  int idx = blockIdx.x*256 + threadIdx.x;
  if (idx >= 64*192) return;
  int o = idx / 192, k = idx % 192;
  float v = 0.f;
  if (o < 2) v = frw[o*192+k]; else if (o < 34) v = fgw[(o-2)*192+k];
  w_pad[idx] = v;
  if (k == 0){
    float bv = 0.f;
    if (o < 2) bv = frb[o]; else if (o < 34) bv = fgb[o-2];
    b_pad[o] = bv;
  }
}

// ---------------- wide Kalman prep ----------------
__global__ void kalman_prep_kernel(const float* __restrict__ raw, float* __restrict__ rp, int nrows){
  int idx = blockIdx.x*256 + threadIdx.x;
  if (idx >= nrows*32) return;
  int d  = idx & 31;
  int bt = idx >> 5;
  const float* r = raw + (size_t)bt*64;
  float* o = rp + (size_t)bt*34;
  o[2+d] = sigm(r[2+d]);
  if (d==0){
    float rho = 1.25f*sigm(r[0]);
    float phi = PI_F * tanhf(r[1]);
    o[0] = rho*cosf(phi);
    o[1] = rho*sinf(phi);
  }
}

// ---------------- sequential Kalman scan (FMA-only) ----------------
__global__ __launch_bounds__(64) void kalman_scan_kernel(
  const float* __restrict__ x_c, const float* __restrict__ rp, float* __restrict__ xpost,
  int b0, int Bc)
{
  const int lane = threadIdx.x;
  const int bl = blockIdx.x*4 + (lane>>4);
  if (bl >= Bc) return;
  const int m = lane & 15;
  const float* xb  = x_c + (size_t)bl*Q_*D_;
  const float* rpb = rp  + (size_t)bl*Q_*34;
  float re = xb[m], im = xb[16+m];
  for (int t=0;t<Q_;t++){
    const float* r = rpb + (size_t)t*34;
    float rc = r[0], rs = r[1];
    float g0 = r[2+m], g1 = r[18+m];
    float y0 = xb[(size_t)t*D_ + m], y1v = xb[(size_t)t*D_ + 16 + m];
    float pr  = rc*re - rs*im;
    float pim = rs*re + rc*im;
    re = pr  + g0*(y0  - pr);
    im = pim + g1*(y1v - pim);
  }
  xpost[(b0+bl)*D_ + m] = re;
  xpost[(b0+bl)*D_ + 16 + m] = im;
}

// ---------------- rollout weight prep: wT1[k][o] + packed [k][o][8] gate block ----------------
__global__ void prep_rollout_kernel(const float* __restrict__ riw, const float* __restrict__ wih,
                                    const float* __restrict__ whh,
                                    float* __restrict__ wT1, float* __restrict__ wPack)
{
  int idx = blockIdx.x*256 + threadIdx.x;
  if (idx < 224*192){
    int o = idx % 192, k = idx / 192;
    wT1[idx] = riw[o*224 + k];
    return;
  }
  idx -= 224*192;
  if (idx < 192*192){
    int o = idx % 192, k = idx / 192;
    float* w = wPack + ((size_t)k*192 + o)*8;
    w[0] = wih[(0*192+o)*192 + k];
    w[1] = wih[(1*192+o)*192 + k];
    w[2] = wih[(2*192+o)*192 + k];
    w[3] = whh[(0*192+o)*192 + k];
    w[4] = whh[(1*192+o)*192 + k];
    w[5] = whh[(2*192+o)*192 + k];
    w[6] = 0.f; w[7] = 0.f;
  }
}

// ---------------- GRU rollout v4: ALL weights in VGPRs, zero vmem in the step loop ----------------
// - phase-A weights: 56 regs/thread; phase-B weights: 288 regs/thread (48k x 6 gates),
//   fully-unrolled static indexing -> stays in VGPRs (rule: no runtime idx).
// - LDS state packed float4: h4/x4[k>>1][(k&1)*2+j] -> one ds_read_b128 serves 2 k's x 2 batches.
// - FP accumulation order identical to v3 (same k-sequence per quarter).
// - ~390 VGPRs/thread; launch_bounds(768,3) caps at 682 -> no spill; 3 waves/SIMD fits pool.
__global__ __launch_bounds__(RT_,3) void rollout_kernel(
  const float* __restrict__ hlast, const float* __restrict__ xpost,
  const float* __restrict__ wT1,  const float* __restrict__ rib_,
  const float* __restrict__ wPack,
  const float* __restrict__ bih,  const float* __restrict__ bhh,
  const float* __restrict__ lnw,  const float* __restrict__ lnb,
  const float* __restrict__ frw,  const float* __restrict__ frb,
  float* __restrict__ out)
{
  const int tid = threadIdx.x;
  const int q   = tid / 192;        // quarter 0..3 (wave-aligned: 192 = 3 waves)
  const int o   = tid - q*192;      // channel 0..191
  const int bb  = blockIdx.x*BPB;

  __shared__ float h4[96][4];       // [k>>1][(k&1)*2 + batch]
  __shared__ float x4[96][4];
  __shared__ float c4[16][4];       // Kalman state, same packing (m over 32)
  __shared__ float pA[4][2][192];   // phase-A partials [quarter][batch][o]
  __shared__ float pB[4][12][192];  // phase-B partials [quarter][batch*6+gate][o]
  __shared__ float rsum[2][3][4];   // [batch][wave][S1,S2,S3,S4]

  // ---- init state ----
  if (q < 2){
    h4[o>>1][(o&1)*2+q] = hlast[(size_t)(bb+q)*H_ + o];
    if (o < 32) c4[o>>1][(o&1)*2+q] = xpost[(bb+q)*D_ + o];
  }

  const float w_ln = lnw[o], b_ln = lnb[o];
  const float fr0  = frw[o], fr1  = frw[192+o];
  const float fb0 = frb[0],  fb1 = frb[1];
  const float bi0 = bih[o], bi1 = bih[192+o], bi2 = bih[384+o];
  const float bh0 = bhh[o], bh1 = bhh[192+o], bh2 = bhh[384+o];
  const float rib = rib_[o];
  const float u0 = w_ln*fr0, u1 = w_ln*fr1;      // for fused projection
  const float t0c = b_ln*fr0, t1c = b_ln*fr1;

  // ---- phase-A weights in registers (step-invariant) ----
  float wA[56];
  if (q < 3){
    const int kb = 56*q;
    #pragma unroll
    for (int i=0;i<56;i++) wA[i] = wT1[(kb+i)*192+o];
  } else {
    #pragma unroll
    for (int i=0;i<24;i++) wA[i] = wT1[(168+i)*192+o];
    #pragma unroll
    for (int i=0;i<32;i++) wA[24+i] = wT1[(192+i)*192+o];
  }

  // ---- phase-B weights in registers (step-invariant): 48 k x 6 gates ----
  float wB[48][6];
  {
    const int kb2 = 48*q;
    #pragma unroll
    for (int i=0;i<48;i++){
      const float* wp = wPack + ((size_t)(kb2+i)*192 + o)*8;
      float4 a = *(const float4*)wp;
      float2 b = *(const float2*)(wp+4);
      wB[i][0]=a.x; wB[i][1]=a.y; wB[i][2]=a.z;
      wB[i][3]=a.w; wB[i][4]=b.x; wB[i][5]=b.y;
    }
  }

  // ---- one-time constants: C0=sum(u0), C1=sum(u1), K0=sum(lnb*fr0)+fb0, K1=sum(lnb*fr1)+fb1 ----
  {
    float c0=u0, c1=u1, k0=t0c, k1=t1c;
    #pragma unroll
    for (int off=32; off>0; off>>=1){
      c0 += __shfl_down(c0,off); c1 += __shfl_down(c1,off);
      k0 += __shfl_down(k0,off); k1 += __shfl_down(k1,off);
    }
    if (q==0 && (o&63)==0){
      int w = o>>6;
      rsum[0][w][0]=c0; rsum[0][w][1]=c1; rsum[0][w][2]=k0; rsum[0][w][3]=k1;
    }
  }
  __syncthreads();
  const float C0 = rsum[0][0][0]+rsum[0][1][0]+rsum[0][2][0];
  const float C1 = rsum[0][0][1]+rsum[0][1][1]+rsum[0][2][1];
  const float K0 = rsum[0][0][2]+rsum[0][1][2]+rsum[0][2][2] + fb0;
  const float K1 = rsum[0][0][3]+rsum[0][1][3]+rsum[0][2][3] + fb1;

  for (int s=0; s<WOUT_; s++){
    // ---- phase A: partial x = W1 @ [h;c], K=224 split 4-way, weights+state reg/LDS only ----
    float a0=0.f, a1=0.f;
    if (q < 3){
      const int k20 = 28*q;
      #pragma unroll
      for (int i=0;i<28;i++){
        const float4 hh = *(const float4*)&h4[k20+i][0];
        a0 += wA[2*i]*hh.x;   a1 += wA[2*i]*hh.y;
        a0 += wA[2*i+1]*hh.z; a1 += wA[2*i+1]*hh.w;
      }
    } else {
      #pragma unroll
      for (int i=0;i<12;i++){
        const float4 hh = *(const float4*)&h4[84+i][0];
        a0 += wA[2*i]*hh.x;   a1 += wA[2*i]*hh.y;
        a0 += wA[2*i+1]*hh.z; a1 += wA[2*i+1]*hh.w;
      }
      #pragma unroll
      for (int i=0;i<16;i++){
        const float4 cc = *(const float4*)&c4[i][0];
        a0 += wA[24+2*i]*cc.x;   a1 += wA[24+2*i]*cc.y;
        a0 += wA[24+2*i+1]*cc.z; a1 += wA[24+2*i+1]*cc.w;
      }
    }
    pA[q][0][o]=a0; pA[q][1][o]=a1;
    __syncthreads();

    // ---- x combine: quarter j (<2) owns batch j ----
    if (q < 2){
      x4[o>>1][(o&1)*2+q] = tanhf(rib + pA[0][q][o] + pA[1][q][o] + pA[2][q][o] + pA[3][q][o]);
    }
    __syncthreads();

    // ---- phase B: partial gates, K=192 split 4-way (48 each), weights in regs ----
    float x00=0.f,x01=0.f,x02=0.f, x10=0.f,x11=0.f,x12=0.f;
    float g00=0.f,g01=0.f,g02=0.f, g10=0.f,g11=0.f,g12=0.f;
    {
      const int k20 = 24*q;   // 48q/2
      #pragma unroll
      for (int i=0;i<24;i++){
        const float4 xx = *(const float4*)&x4[k20+i][0];
        const float4 hh = *(const float4*)&h4[k20+i][0];
        // even k
        x00 += wB[2*i][0]*xx.x; x01 += wB[2*i][1]*xx.x; x02 += wB[2*i][2]*xx.x;
        x10 += wB[2*i][0]*xx.y; x11 += wB[2*i][1]*xx.y; x12 += wB[2*i][2]*xx.y;
        g00 += wB[2*i][3]*hh.x; g01 += wB[2*i][4]*hh.x; g02 += wB[2*i][5]*hh.x;
        g10 += wB[2*i][3]*hh.y; g11 += wB[2*i][4]*hh.y; g12 += wB[2*i][5]*hh.y;
        // odd k
        x00 += wB[2*i+1][0]*xx.z; x01 += wB[2*i+1][1]*xx.z; x02 += wB[2*i+1][2]*xx.z;
        x10 += wB[2*i+1][0]*xx.w; x11 += wB[2*i+1][1]*xx.w; x12 += wB[2*i+1][2]*xx.w;
        g00 += wB[2*i+1][3]*hh.z; g01 += wB[2*i+1][4]*hh.z; g02 += wB[2*i+1][5]*hh.z;
        g10 += wB[2*i+1][3]*hh.w; g11 += wB[2*i+1][4]*hh.w; g12 += wB[2*i+1][5]*hh.w;
      }
    }
    pB[q][0][o]=x00;  pB[q][1][o]=x01;  pB[q][2][o]=x02;
    pB[q][3][o]=g00;  pB[q][4][o]=g01;  pB[q][5][o]=g02;
    pB[q][6][o]=x10;  pB[q][7][o]=x11;  pB[q][8][o]=x12;
    pB[q][9][o]=g10;  pB[q][10][o]=g11; pB[q][11][o]=g12;
    __syncthreads();

    // ---- gate combine + fused 4-sum wave reduction (quarters 0/1 own batch q) ----
    float pre = 0.f;
    if (q < 2){
      const int g6 = q*6;
      float P0 = bi0 + pB[0][g6+0][o]+pB[1][g6+0][o]+pB[2][g6+0][o]+pB[3][g6+0][o];
      float P1 = bi1 + pB[0][g6+1][o]+pB[1][g6+1][o]+pB[2][g6+1][o]+pB[3][g6+1][o];
      float P2 = bi2 + pB[0][g6+2][o]+pB[1][g6+2][o]+pB[2][g6+2][o]+pB[3][g6+2][o];
      float Q0 = bh0 + pB[0][g6+3][o]+pB[1][g6+3][o]+pB[2][g6+3][o]+pB[3][g6+3][o];
      float Q1 = bh1 + pB[0][g6+4][o]+pB[1][g6+4][o]+pB[2][g6+4][o]+pB[3][g6+4][o];
      float Q2 = bh2 + pB[0][g6+5][o]+pB[1][g6+5][o]+pB[2][g6+5][o]+pB[3][g6+5][o];
      float rg = sigm(P0+Q0), zz = sigm(P1+Q1);
      float nn = tanhf(P2 + rg*Q2);
      pre = (1.f-zz)*nn + zz*h4[o>>1][(o&1)*2+q];
      float s1 = pre, s2 = pre*pre, s3 = pre*u0, s4 = pre*u1;
      #pragma unroll
      for (int off=32; off>0; off>>=1){
        s1 += __shfl_down(s1,off); s2 += __shfl_down(s2,off);
        s3 += __shfl_down(s3,off); s4 += __shfl_down(s4,off);
      }
      if ((o&63)==0){
        int w = o>>6;
        rsum[q][w][0]=s1; rsum[q][w][1]=s2; rsum[q][w][2]=s3; rsum[q][w][3]=s4;
      }
    }
    __syncthreads();

    // ---- concurrent tail: LN update (q<2) || Kalman rotate (q>=2, o<16) ----
    if (q < 2){
      float S1 = rsum[q][0][0]+rsum[q][1][0]+rsum[q][2][0];
      float S2 = rsum[q][0][1]+rsum[q][1][1]+rsum[q][2][1];
      float mu  = S1*(1.f/192.f);
      float var = S2*(1.f/192.f) - mu*mu;
      float r = rsqrtf(var+1e-5f);
      h4[o>>1][(o&1)*2+q] = (pre-mu)*r*w_ln + b_ln;
    } else if (o < 16){
      const int j = q-2;
      float S1 = rsum[j][0][0]+rsum[j][1][0]+rsum[j][2][0];
      float S2 = rsum[j][0][1]+rsum[j][1][1]+rsum[j][2][1];
      float S3 = rsum[j][0][2]+rsum[j][1][2]+rsum[j][2][2];
      float S4 = rsum[j][0][3]+rsum[j][1][3]+rsum[j][2][3];
      float mu  = S1*(1.f/192.f);
      float var = S2*(1.f/192.f) - mu*mu;
      float r = rsqrtf(var+1e-5f);
      float proj0 = r*(S3 - mu*C0) + K0;
      float proj1 = r*(S4 - mu*C1) + K1;
      float rho = 1.25f*sigm(proj0);
      float phi = PI_F*tanhf(proj1);
      float rc = rho*cosf(phi), rs = rho*sinf(phi);
      float re = c4[o>>1][(o&1)*2+j];
      float im = c4[8+(o>>1)][(o&1)*2+j];
      float nre = rc*re - rs*im;
      float nim = rs*re + rc*im;
      c4[o>>1][(o&1)*2+j] = nre;
      c4[8+(o>>1)][(o&1)*2+j] = nim;
      float* ob = out + ((size_t)(bb+j)*WOUT_ + s)*D_;
      ob[o] = nre; ob[o+16] = nim;
    }
    __syncthreads();
  }
}

// ---------------- host launch ----------------
extern "C" void kernel_launch(void* const* d_in, const int* in_sizes, int n_in,
                              void* d_out, int out_size, void* d_ws, size_t ws_size,
                              hipStream_t stream)
{
  const float* x_in     = (const float*)d_in[0];
  const float* inp_w    = (const float*)d_in[1];
  const float* inp_b    = (const float*)d_in[2];
  const float* b_dw_w   = (const float*)d_in[3];
  const float* b_dw_b   = (const float*)d_in[4];
  const float* b_ln_w   = (const float*)d_in[5];
  const float* b_ln_b   = (const float*)d_in[6];
  const float* b_pw1_w  = (const float*)d_in[7];
  const float* b_pw1_b  = (const float*)d_in[8];
  const float* b_grn_g  = (const float*)d_in[9];
  const float* b_grn_b  = (const float*)d_in[10];
  const float* b_pw2_w  = (const float*)d_in[11];
  const float* b_pw2_b  = (const float*)d_in[12];
  const float* out_ln_w = (const float*)d_in[13];
  const float* out_ln_b = (const float*)d_in[14];
  const float* fc_rp_w  = (const float*)d_in[15];
  const float* fc_rp_b  = (const float*)d_in[16];
  const float* fc_gain_w= (const float*)d_in[17];
  const float* fc_gain_b= (const float*)d_in[18];
  const float* roll_in_w= (const float*)d_in[19];
  const float* roll_in_b= (const float*)d_in[20];
  const float* gru_wih  = (const float*)d_in[21];
  const float* gru_whh  = (const float*)d_in[22];
  const float* gru_bih  = (const float*)d_in[23];
  const float* gru_bhh  = (const float*)d_in[24];
  const float* roll_ln_w= (const float*)d_in[25];
  const float* roll_ln_b= (const float*)d_in[26];
  const float* fc_rp_r_w= (const float*)d_in[27];
  const float* fc_rp_r_b= (const float*)d_in[28];
  float* out = (float*)d_out;

  // ---- adaptive chunking ----
  // per-row floats: h(192) + yln(192) + mid(384; feats/y1, then rpraw(64)+rp(34)) = 768
  // fixed tail: scaleB 98304 + w_pad 12288 + b_pad 64 + xpost 8192 + hlast 49152
  //           + wT1 43008 + wPack 294912 = 505920 ; + margin
  const size_t SMAL_FLOATS = 505920 + 4096;
  size_t ws_floats = ws_size / 4;
  int nchunk = 256;
  const int cand[9] = {1,2,4,8,16,32,64,128,256};
  for (int ci=0; ci<9; ci++){
    size_t Mc_try = (size_t)M_ / cand[ci];
    if (Mc_try*768 + SMAL_FLOATS <= ws_floats){ nchunk = cand[ci]; break; }
  }
  const int    Bc = B_ / nchunk;
  const size_t Mc = (size_t)Bc * Q_;

  float* ws    = (float*)d_ws;
  float* h_c   = ws;
  float* yln_c = h_c   + Mc*192;
  float* mid_c = yln_c + Mc*192;
  float* smal  = mid_c + Mc*384;

  float* feats_c = mid_c;
  float* y1_c    = mid_c;
  float* rpraw   = mid_c;                // Mc*64 (y1 dead by then)
  float* rp_c    = mid_c + Mc*64;        // Mc*34

  float* scaleB = smal;                  // Bc*384 (reserve 98304)
  float* w_pad  = smal + 98304;          // 64*192
  float* b_pad  = w_pad + 12288;         // 64
  float* xpost  = b_pad + 64;            // B_*32
  float* hlast  = xpost + 8192;          // B_*192
  float* wT1    = hlast + 49152;         // 224*192
  float* wPack  = wT1 + 43008;           // 192*192*8

  // one-time weight prep
  pack_w_kernel<<<(64*192+255)/256, 256, 0, stream>>>(fc_rp_w, fc_rp_b, fc_gain_w, fc_gain_b, w_pad, b_pad);
  prep_rollout_kernel<<<(224*192+192*192+255)/256, 256, 0, stream>>>(roll_in_w, gru_wih, gru_whh, wT1, wPack);

  const int gmx = (int)(Mc/64);
  for (int ch=0; ch<nchunk; ch++){
    const float* x_c = x_in + (size_t)ch*Mc*D_;
    // 1. features + input projection
    feats_kernel<<<(int)((Mc*32+255)/256), 256, 0, stream>>>(x_c, feats_c, (int)Mc);
    gemm_t64<0><<<dim3(gmx, 3), 256, 0, stream>>>(feats_c, inp_w, inp_b,
                                                  h_c, nullptr, nullptr, H_, INCH_);
    // 2. ConvNeXt blocks
    for (int blk = 0; blk < 2; blk++){
      const float* dww = b_dw_w + blk*H_*9;     const float* dwb = b_dw_b + blk*H_;
      const float* lnw = b_ln_w + blk*H_;       const float* lnb = b_ln_b + blk*H_;
      const float* p1w = b_pw1_w + blk*HID_*H_; const float* p1b = b_pw1_b + blk*HID_;
      const float* gg  = b_grn_g + blk*HID_;    const float* gb  = b_grn_b + blk*HID_;
      const float* p2w = b_pw2_w + blk*H_*HID_; const float* p2b = b_pw2_b + blk*H_;
      dwconv_ln4<<<(int)(Mc/4), 192, 0, stream>>>(h_c, dww, dwb, lnw, lnb, yln_c);
      gemm_t64<1><<<dim3(gmx, 6), 256, 0, stream>>>(yln_c, p1w, p1b,
                                                    y1_c, nullptr, nullptr, HID_, H_);
      grn_stats_kernel<<<Bc, 384, 0, stream>>>(y1_c, gg, scaleB);
      gemm_t64<2><<<dim3(gmx, 3), 256, 0, stream>>>(y1_c, p2w, p2b,
                                                    h_c, scaleB, gb, H_, HID_);
    }
    // 3. output LN -> h_seq, save last-t rows
    out_ln_kernel<<<(int)Mc, 192, 0, stream>>>(h_c, out_ln_w, out_ln_b, yln_c, hlast, ch*Bc);
    // 4. Kalman projection + wide transcendental prep + FMA-only scan
    gemm_t64<0><<<dim3(gmx, 1), 256, 0, stream>>>(yln_c, w_pad, b_pad,
                                                  rpraw, nullptr, nullptr, 64, H_);
    kalman_prep_kernel<<<(int)((Mc*32+255)/256), 256, 0, stream>>>(rpraw, rp_c, (int)Mc);
    kalman_scan_kernel<<<(Bc+3)/4, 64, 0, stream>>>(x_c, rp_c, xpost, ch*Bc, Bc);
  }
  // 5. GRU rollout v4: 128 blocks x 768 threads, all weights in VGPRs
  rollout_kernel<<<B_/BPB, RT_, 0, stream>>>(hlast, xpost, wT1, roll_in_b, wPack,
                                             gru_bih, gru_bhh, roll_ln_w, roll_ln_b,
                                             fc_rp_r_w, fc_rp_r_b, out);
  (void)in_sizes; (void)n_in; (void)out_size; (void)ws_size;
}

// Round 4
// 2603.331 us; speedup vs baseline: 1.6366x; 1.6366x over previous
//
#include <hip/hip_runtime.h>
#include <cstdint>
#include <cstddef>

#define B_    256
#define Q_    512
#define D_    32
#define H_    192
#define HID_  384
#define INCH_ 96
#define M_    (B_*Q_)    // 131072
#define WOUT_ 64
#define BPB   2          // batches per rollout block
#define RT_   768        // rollout threads: 4 quarters x 192, 12 waves
#define PI_F  3.14159265358979323846f

typedef unsigned int uint_t;

__device__ __forceinline__ float sigm(float x){ return 1.f/(1.f+expf(-x)); }
__device__ __forceinline__ float gelu_exact(float x){ return 0.5f*x*(1.f+erff(x*0.7071067811865475f)); }

// ---------------- features: [x, dy, ddy] ----------------
__global__ void feats_kernel(const float* __restrict__ x, float* __restrict__ feats, int nrows){
  int idx = blockIdx.x*256 + threadIdx.x;
  if (idx >= nrows*32) return;
  int d  = idx & 31;
  int bt = idx >> 5;
  int t  = bt & 511;
  const float* xr = x + (size_t)bt*D_;
  float xc  = xr[d];
  float xm1 = (t>0) ? xr[d - D_]   : 0.f;
  float xm2 = (t>1) ? xr[d - 2*D_] : 0.f;
  float dy   = (t>0) ? xc - xm1   : 0.f;
  float dym1 = (t>1) ? xm1 - xm2  : 0.f;
  float ddy  = (t>0) ? dy - dym1  : 0.f;
  float* fr = feats + (size_t)bt*INCH_;
  fr[d] = xc; fr[D_+d] = dy; fr[2*D_+d] = ddy;
}

// ---------------- 128x64x8 fp32 tiled GEMM, 4 blocks/CU, acc[8][4] ----------------
// MODE 0: out = acc+bias ; MODE 1: out = gelu(acc+bias) ; MODE 2: A affine, C += acc+bias
// K accumulation order is k-ascending per output element (numerically identical to the
// previous 64x64 version).
template<int MODE>
__global__ __launch_bounds__(256,4) void gemm_t128(
    const float* __restrict__ Af,
    const float* __restrict__ W,  const float* __restrict__ bias,
    float* __restrict__ Cf,
    const float* __restrict__ scale, const float* __restrict__ grnb,
    int N, int K)
{
  __shared__ float As[8][128];
  __shared__ float Bs[8][64];
  const int tid = threadIdx.x;
  const int bm = blockIdx.x*128, bn = blockIdx.y*64;
  const int tx = tid & 15, ty = tid >> 4;          // tx: 16 col-groups, ty: 16 row-groups
  const int arow = tid >> 1,        ak = (tid & 1)*4;   // A: 128 rows x 2 threads
  const int brow = (tid & 127) >> 1, bk = (tid & 1)*4;  // B: 64 rows x 2 threads (tid<128)
  const float* srow = (MODE==2) ? (scale + (size_t)(bm>>9)*HID_) : nullptr;

  float acc[8][4];
  #pragma unroll
  for (int i=0;i<8;i++)
    #pragma unroll
    for (int j=0;j<4;j++) acc[i][j]=0.f;

  const float* gA = Af + (size_t)(bm+arow)*K;
  const float* gB = W  + (size_t)(bn+brow)*K;

  for (int k0=0;k0<K;k0+=8){
    float4 va = *(const float4*)(gA + k0 + ak);
    float4 vb;
    if (tid < 128) vb = *(const float4*)(gB + k0 + bk);
    if (MODE==2){
      int c = k0+ak;
      float4 sc = *(const float4*)(srow+c);
      float4 gb = *(const float4*)(grnb+c);
      va.x = va.x*sc.x+gb.x; va.y = va.y*sc.y+gb.y;
      va.z = va.z*sc.z+gb.z; va.w = va.w*sc.w+gb.w;
    }
    As[ak+0][arow]=va.x; As[ak+1][arow]=va.y; As[ak+2][arow]=va.z; As[ak+3][arow]=va.w;
    if (tid < 128){
      Bs[bk+0][brow]=vb.x; Bs[bk+1][brow]=vb.y; Bs[bk+2][brow]=vb.z; Bs[bk+3][brow]=vb.w;
    }
    __syncthreads();
    #pragma unroll
    for (int kk=0;kk<8;kk++){
      float4 a0 = *(const float4*)&As[kk][ty*8];
      float4 a1 = *(const float4*)&As[kk][ty*8+4];
      float4 b  = *(const float4*)&Bs[kk][tx*4];
      float ar[8] = {a0.x,a0.y,a0.z,a0.w,a1.x,a1.y,a1.z,a1.w};
      #pragma unroll
      for (int i=0;i<8;i++){
        acc[i][0] += ar[i]*b.x; acc[i][1] += ar[i]*b.y;
        acc[i][2] += ar[i]*b.z; acc[i][3] += ar[i]*b.w;
      }
    }
    __syncthreads();
  }

  const int o0 = bn + tx*4;
  float4 b0 = *(const float4*)(bias + o0);
  #pragma unroll
  for (int i=0;i<8;i++){
    int m = bm + ty*8 + i;
    if (MODE==0){
      float4 v; v.x=acc[i][0]+b0.x; v.y=acc[i][1]+b0.y; v.z=acc[i][2]+b0.z; v.w=acc[i][3]+b0.w;
      *(float4*)(Cf + (size_t)m*N + o0) = v;
    } else if (MODE==1){
      float4 v;
      v.x = gelu_exact(acc[i][0]+b0.x); v.y = gelu_exact(acc[i][1]+b0.y);
      v.z = gelu_exact(acc[i][2]+b0.z); v.w = gelu_exact(acc[i][3]+b0.w);
      *(float4*)(Cf + (size_t)m*N + o0) = v;
    } else {
      float4 old = *(const float4*)(Cf + (size_t)m*N + o0);
      float4 v; v.x=old.x+acc[i][0]+b0.x; v.y=old.y+acc[i][1]+b0.y;
      v.z=old.z+acc[i][2]+b0.z; v.w=old.w+acc[i][3]+b0.w;
      *(float4*)(Cf + (size_t)m*N + o0) = v;
    }
  }
}

// ---------------- depthwise conv (k=9, edge pad) + LN, 4 timesteps per block ----------------
__global__ __launch_bounds__(192) void dwconv_ln4(
  const float* __restrict__ h, const float* __restrict__ dww, const float* __restrict__ dwb,
  const float* __restrict__ lnw, const float* __restrict__ lnb, float* __restrict__ yln)
{
  __shared__ float sh[12][192];
  __shared__ float rs_[192], rq_[192], st[2];
  const int c  = threadIdx.x;
  const int t0 = (blockIdx.x & 127) * 4;
  const size_t base = (size_t)(blockIdx.x >> 7) * Q_ * H_;
  #pragma unroll
  for (int r=0;r<12;r++){
    int tt = t0 - 4 + r; tt = tt<0?0:(tt>511?511:tt);
    sh[r][c] = h[base + (size_t)tt*H_ + c];
  }
  float w[9];
  #pragma unroll
  for (int k=0;k<9;k++) w[k] = dww[c*9+k];
  const float dbias = dwb[c], lw = lnw[c], lb = lnb[c];
  __syncthreads();
  for (int i=0;i<4;i++){
    float acc = dbias;
    #pragma unroll
    for (int k=0;k<9;k++) acc += w[k]*sh[i+k][c];
    rs_[c]=acc; rq_[c]=acc*acc;
    __syncthreads();
    if (c < 64){
      float s = rs_[c]+rs_[c+64]+rs_[c+128];
      float q = rq_[c]+rq_[c+64]+rq_[c+128];
      #pragma unroll
      for (int off=32; off>0; off>>=1){ s += __shfl_down(s,off); q += __shfl_down(q,off); }
      if (c==0){ st[0]=s; st[1]=q; }
    }
    __syncthreads();
    float mean = st[0]*(1.f/H_);
    float var  = st[1]*(1.f/H_) - mean*mean;
    float r = rsqrtf(var + 1e-5f);
    yln[base + (size_t)(t0+i)*H_ + c] = (acc-mean)*r*lw + lb;
  }
}

// ---------------- output LayerNorm (+ save last-timestep row) ----------------
__global__ __launch_bounds__(192) void out_ln_kernel(
  const float* __restrict__ h, const float* __restrict__ lnw, const float* __restrict__ lnb,
  float* __restrict__ o, float* __restrict__ hlast, int b0)
{
  __shared__ float rs_[192], rq_[192], st[2];
  const int c  = threadIdx.x;
  const int bt = blockIdx.x;
  float v = h[(size_t)bt*H_ + c];
  rs_[c]=v; rq_[c]=v*v;
  __syncthreads();
  if (c < 64){
    float s = rs_[c]+rs_[c+64]+rs_[c+128];
    float q = rq_[c]+rq_[c+64]+rq_[c+128];
    #pragma unroll
    for (int off=32; off>0; off>>=1){ s += __shfl_down(s,off); q += __shfl_down(q,off); }
    if (c==0){ st[0]=s; st[1]=q; }
  }
  __syncthreads();
  float mean = st[0]*(1.f/H_);
  float var  = st[1]*(1.f/H_) - mean*mean;
  float r = rsqrtf(var + 1e-5f);
  float res = (v-mean)*r*lnw[c] + lnb[c];
  o[(size_t)bt*H_ + c] = res;
  if ((bt & 511) == 511) hlast[(size_t)(b0 + (bt>>9))*H_ + c] = res;
}

// ---------------- GRN stats ----------------
__global__ __launch_bounds__(384) void grn_stats_kernel(
  const float* __restrict__ y1, const float* __restrict__ grn_g, float* __restrict__ scale)
{
  __shared__ float r[384];
  const int c = threadIdx.x;
  const int b = blockIdx.x;
  const float* p = y1 + (size_t)b*Q_*HID_ + c;
  float s = 0.f;
  #pragma unroll 8
  for (int t=0;t<Q_;t++){ float v = p[(size_t)t*HID_]; s += v*v; }
  float gx = sqrtf(s);
  r[c] = gx;
  __syncthreads();
  if (c < 64){
    float v = r[c]+r[c+64]+r[c+128]+r[c+192]+r[c+256]+r[c+320];
    #pragma unroll
    for (int off=32; off>0; off>>=1) v += __shfl_down(v,off);
    if (c==0) r[0]=v;
  }
  __syncthreads();
  float mean = r[0]*(1.f/HID_);
  scale[(size_t)b*HID_ + c] = 1.f + grn_g[c]*gx/(mean + 1e-6f);
}

// ---------------- pack fc_rp / fc_gain into padded (64,192) W ----------------
__global__ void pack_w_kernel(const float* __restrict__ frw, const float* __restrict__ frb,
                              const float* __restrict__ fgw, const float* __restrict__ fgb,
                              float* __restrict__ w_pad, float* __restrict__ b_pad)
{
  int idx = blockIdx.x*256 + threadIdx.x;
  if (idx >= 64*192) return;
  int o = idx / 192, k = idx % 192;
  float v = 0.f;
  if (o < 2) v = frw[o*192+k]; else if (o < 34) v = fgw[(o-2)*192+k];
  w_pad[idx] = v;
  if (k == 0){
    float bv = 0.f;
    if (o < 2) bv = frb[o]; else if (o < 34) bv = fgb[o-2];
    b_pad[o] = bv;
  }
}

// ---------------- wide Kalman prep ----------------
__global__ void kalman_prep_kernel(const float* __restrict__ raw, float* __restrict__ rp, int nrows){
  int idx = blockIdx.x*256 + threadIdx.x;
  if (idx >= nrows*32) return;
  int d  = idx & 31;
  int bt = idx >> 5;
  const float* r = raw + (size_t)bt*64;
  float* o = rp + (size_t)bt*34;
  o[2+d] = sigm(r[2+d]);
  if (d==0){
    float rho = 1.25f*sigm(r[0]);
    float phi = PI_F * tanhf(r[1]);
    o[0] = rho*cosf(phi);
    o[1] = rho*sinf(phi);
  }
}

// ---------------- sequential Kalman scan (FMA-only) ----------------
__global__ __launch_bounds__(64) void kalman_scan_kernel(
  const float* __restrict__ x_c, const float* __restrict__ rp, float* __restrict__ xpost,
  int b0, int Bc)
{
  const int lane = threadIdx.x;
  const int bl = blockIdx.x*4 + (lane>>4);
  if (bl >= Bc) return;
  const int m = lane & 15;
  const float* xb  = x_c + (size_t)bl*Q_*D_;
  const float* rpb = rp  + (size_t)bl*Q_*34;
  float re = xb[m], im = xb[16+m];
  for (int t=0;t<Q_;t++){
    const float* r = rpb + (size_t)t*34;
    float rc = r[0], rs = r[1];
    float g0 = r[2+m], g1 = r[18+m];
    float y0 = xb[(size_t)t*D_ + m], y1v = xb[(size_t)t*D_ + 16 + m];
    float pr  = rc*re - rs*im;
    float pim = rs*re + rc*im;
    re = pr  + g0*(y0  - pr);
    im = pim + g1*(y1v - pim);
  }
  xpost[(b0+bl)*D_ + m] = re;
  xpost[(b0+bl)*D_ + 16 + m] = im;
}

// ---------------- rollout weight prep: wT1[k][o] + packed [k][o][8] gate block ----------------
__global__ void prep_rollout_kernel(const float* __restrict__ riw, const float* __restrict__ wih,
                                    const float* __restrict__ whh,
                                    float* __restrict__ wT1, float* __restrict__ wPack)
{
  int idx = blockIdx.x*256 + threadIdx.x;
  if (idx < 224*192){
    int o = idx % 192, k = idx / 192;
    wT1[idx] = riw[o*224 + k];
    return;
  }
  idx -= 224*192;
  if (idx < 192*192){
    int o = idx % 192, k = idx / 192;
    float* w = wPack + ((size_t)k*192 + o)*8;
    w[0] = wih[(0*192+o)*192 + k];
    w[1] = wih[(1*192+o)*192 + k];
    w[2] = wih[(2*192+o)*192 + k];
    w[3] = whh[(0*192+o)*192 + k];
    w[4] = whh[(1*192+o)*192 + k];
    w[5] = whh[(2*192+o)*192 + k];
    w[6] = 0.f; w[7] = 0.f;
  }
}

// ---------------- GRU rollout v3 (reverted from v4 spill regression): BPB=2, 128 blocks ----------------
// - wT1 (phase-A weights) live in 56 registers per thread, loaded once (step-invariant).
//   NOTE: phase-B weights stay as L2 streams; promoting them (288 floats) exceeds SROA's
//   limit and spills to scratch (R3: 3.5 GB scratch traffic, 2.3 ms). Do not retry.
// - Single fused reduction per step; LN-update and Kalman-rotate run concurrently.
__global__ __launch_bounds__(RT_,3) void rollout_kernel(
  const float* __restrict__ hlast, const float* __restrict__ xpost,
  const float* __restrict__ wT1,  const float* __restrict__ rib_,
  const float* __restrict__ wPack,
  const float* __restrict__ bih,  const float* __restrict__ bhh,
  const float* __restrict__ lnw,  const float* __restrict__ lnb,
  const float* __restrict__ frw,  const float* __restrict__ frb,
  float* __restrict__ out)
{
  const int tid = threadIdx.x;
  const int q   = tid / 192;        // quarter 0..3 (wave-aligned: 192 = 3 waves)
  const int o   = tid - q*192;      // channel 0..191
  const int bb  = blockIdx.x*BPB;

  __shared__ float hT[192][2];      // h state, batch-major
  __shared__ float xT[192][2];      // x = tanh(W1 [h;c]), batch-major
  __shared__ float cT[32][2];       // curr (Kalman state), batch-major
  __shared__ float pA[4][2][192];   // phase-A partials [quarter][batch][o]
  __shared__ float pB[4][12][192];  // phase-B partials [quarter][batch*6+gate][o]
  __shared__ float rsum[2][3][4];   // [batch][wave][S1,S2,S3,S4]

  // ---- init state ----
  if (q < 2){
    hT[o][q] = hlast[(size_t)(bb+q)*H_ + o];
    if (o < 32) cT[o][q] = xpost[(bb+q)*D_ + o];
  }

  const float w_ln = lnw[o], b_ln = lnb[o];
  const float fr0  = frw[o], fr1  = frw[192+o];
  const float fb0 = frb[0],  fb1 = frb[1];
  const float bi0 = bih[o], bi1 = bih[192+o], bi2 = bih[384+o];
  const float bh0 = bhh[o], bh1 = bhh[192+o], bh2 = bhh[384+o];
  const float rib = rib_[o];
  const float u0 = w_ln*fr0, u1 = w_ln*fr1;      // for fused projection
  const float t0c = b_ln*fr0, t1c = b_ln*fr1;

  // ---- phase-A weights in registers (step-invariant) ----
  float wreg[56];
  if (q < 3){
    const int kb = 56*q;
    #pragma unroll
    for (int i=0;i<56;i++) wreg[i] = wT1[(kb+i)*192+o];
  } else {
    #pragma unroll
    for (int i=0;i<24;i++) wreg[i] = wT1[(168+i)*192+o];
    #pragma unroll
    for (int i=0;i<32;i++) wreg[24+i] = wT1[(192+i)*192+o];
  }

  // ---- one-time constants: C0=sum(u0), C1=sum(u1), K0=sum(lnb*fr0)+fb0, K1=sum(lnb*fr1)+fb1 ----
  {
    float c0=u0, c1=u1, k0=t0c, k1=t1c;
    #pragma unroll
    for (int off=32; off>0; off>>=1){
      c0 += __shfl_down(c0,off); c1 += __shfl_down(c1,off);
      k0 += __shfl_down(k0,off); k1 += __shfl_down(k1,off);
    }
    if (q==0 && (o&63)==0){
      int w = o>>6;
      rsum[0][w][0]=c0; rsum[0][w][1]=c1; rsum[0][w][2]=k0; rsum[0][w][3]=k1;
    }
  }
  __syncthreads();
  const float C0 = rsum[0][0][0]+rsum[0][1][0]+rsum[0][2][0];
  const float C1 = rsum[0][0][1]+rsum[0][1][1]+rsum[0][2][1];
  const float K0 = rsum[0][0][2]+rsum[0][1][2]+rsum[0][2][2] + fb0;
  const float K1 = rsum[0][0][3]+rsum[0][1][3]+rsum[0][2][3] + fb1;

  for (int s=0; s<WOUT_; s++){
    // ---- phase A: partial x = W1 @ [h;c], K=224 split 4-way, weights in regs ----
    float a0=0.f, a1=0.f;
    if (q < 3){
      const int kb = 56*q;
      #pragma unroll
      for (int i=0;i<56;i++){
        float2 h2 = *(const float2*)&hT[kb+i][0];
        a0 += wreg[i]*h2.x; a1 += wreg[i]*h2.y;
      }
    } else {
      #pragma unroll
      for (int i=0;i<24;i++){
        float2 h2 = *(const float2*)&hT[168+i][0];
        a0 += wreg[i]*h2.x; a1 += wreg[i]*h2.y;
      }
      #pragma unroll
      for (int i=0;i<32;i++){
        float2 c2 = *(const float2*)&cT[i][0];
        a0 += wreg[24+i]*c2.x; a1 += wreg[24+i]*c2.y;
      }
    }
    pA[q][0][o]=a0; pA[q][1][o]=a1;
    __syncthreads();

    // ---- x combine: quarter j (<2) owns batch j ----
    if (q < 2){
      xT[o][q] = tanhf(rib + pA[0][q][o] + pA[1][q][o] + pA[2][q][o] + pA[3][q][o]);
    }
    __syncthreads();

    // ---- phase B: partial gates, K=192 split 4-way (48 each) ----
    float accx[2][3] = {{0.f,0.f,0.f},{0.f,0.f,0.f}};
    float acch[2][3] = {{0.f,0.f,0.f},{0.f,0.f,0.f}};
    {
      const int kb2 = 48*q;
      #pragma unroll 4
      for (int i=0;i<48;i++){
        const int k = kb2+i;
        const float4* wp = (const float4*)(wPack + ((size_t)k*192 + o)*8);
        const float4 wA = wp[0];
        const float4 wB = wp[1];
        const float2 xx = *(const float2*)&xT[k][0];
        const float2 hh = *(const float2*)&hT[k][0];
        accx[0][0] += wA.x*xx.x; accx[0][1] += wA.y*xx.x; accx[0][2] += wA.z*xx.x;
        accx[1][0] += wA.x*xx.y; accx[1][1] += wA.y*xx.y; accx[1][2] += wA.z*xx.y;
        acch[0][0] += wA.w*hh.x; acch[0][1] += wB.x*hh.x; acch[0][2] += wB.y*hh.x;
        acch[1][0] += wA.w*hh.y; acch[1][1] += wB.x*hh.y; acch[1][2] += wB.y*hh.y;
      }
    }
    #pragma unroll
    for (int j=0;j<2;j++){
      #pragma unroll
      for (int g=0;g<3;g++){
        pB[q][j*6+g][o]   = accx[j][g];
        pB[q][j*6+3+g][o] = acch[j][g];
      }
    }
    __syncthreads();

    // ---- gate combine + fused 4-sum wave reduction (quarters 0/1 own batch q) ----
    float pre = 0.f;
    if (q < 2){
      const int g6 = q*6;
      float P0 = bi0 + pB[0][g6+0][o]+pB[1][g6+0][o]+pB[2][g6+0][o]+pB[3][g6+0][o];
      float P1 = bi1 + pB[0][g6+1][o]+pB[1][g6+1][o]+pB[2][g6+1][o]+pB[3][g6+1][o];
      float P2 = bi2 + pB[0][g6+2][o]+pB[1][g6+2][o]+pB[2][g6+2][o]+pB[3][g6+2][o];
      float Q0 = bh0 + pB[0][g6+3][o]+pB[1][g6+3][o]+pB[2][g6+3][o]+pB[3][g6+3][o];
      float Q1 = bh1 + pB[0][g6+4][o]+pB[1][g6+4][o]+pB[2][g6+4][o]+pB[3][g6+4][o];
      float Q2 = bh2 + pB[0][g6+5][o]+pB[1][g6+5][o]+pB[2][g6+5][o]+pB[3][g6+5][o];
      float rg = sigm(P0+Q0), zz = sigm(P1+Q1);
      float nn = tanhf(P2 + rg*Q2);
      pre = (1.f-zz)*nn + zz*hT[o][q];
      float s1 = pre, s2 = pre*pre, s3 = pre*u0, s4 = pre*u1;
      #pragma unroll
      for (int off=32; off>0; off>>=1){
        s1 += __shfl_down(s1,off); s2 += __shfl_down(s2,off);
        s3 += __shfl_down(s3,off); s4 += __shfl_down(s4,off);
      }
      if ((o&63)==0){
        int w = o>>6;
        rsum[q][w][0]=s1; rsum[q][w][1]=s2; rsum[q][w][2]=s3; rsum[q][w][3]=s4;
      }
    }
    __syncthreads();

    // ---- concurrent tail: LN update (q<2) || Kalman rotate (q>=2, o<16) ----
    if (q < 2){
      float S1 = rsum[q][0][0]+rsum[q][1][0]+rsum[q][2][0];
      float S2 = rsum[q][0][1]+rsum[q][1][1]+rsum[q][2][1];
      float mu  = S1*(1.f/192.f);
      float var = S2*(1.f/192.f) - mu*mu;
      float r = rsqrtf(var+1e-5f);
      hT[o][q] = (pre-mu)*r*w_ln + b_ln;
    } else if (o < 16){
      const int j = q-2;
      float S1 = rsum[j][0][0]+rsum[j][1][0]+rsum[j][2][0];
      float S2 = rsum[j][0][1]+rsum[j][1][1]+rsum[j][2][1];
      float S3 = rsum[j][0][2]+rsum[j][1][2]+rsum[j][2][2];
      float S4 = rsum[j][0][3]+rsum[j][1][3]+rsum[j][2][3];
      float mu  = S1*(1.f/192.f);
      float var = S2*(1.f/192.f) - mu*mu;
      float r = rsqrtf(var+1e-5f);
      float proj0 = r*(S3 - mu*C0) + K0;
      float proj1 = r*(S4 - mu*C1) + K1;
      float rho = 1.25f*sigm(proj0);
      float phi = PI_F*tanhf(proj1);
      float rc = rho*cosf(phi), rs = rho*sinf(phi);
      float re = cT[o][j], im = cT[o+16][j];
      float nre = rc*re - rs*im;
      float nim = rs*re + rc*im;
      cT[o][j] = nre; cT[o+16][j] = nim;
      float* ob = out + ((size_t)(bb+j)*WOUT_ + s)*D_;
      ob[o] = nre; ob[o+16] = nim;
    }
    __syncthreads();
  }
}

// ---------------- host launch ----------------
extern "C" void kernel_launch(void* const* d_in, const int* in_sizes, int n_in,
                              void* d_out, int out_size, void* d_ws, size_t ws_size,
                              hipStream_t stream)
{
  const float* x_in     = (const float*)d_in[0];
  const float* inp_w    = (const float*)d_in[1];
  const float* inp_b    = (const float*)d_in[2];
  const float* b_dw_w   = (const float*)d_in[3];
  const float* b_dw_b   = (const float*)d_in[4];
  const float* b_ln_w   = (const float*)d_in[5];
  const float* b_ln_b   = (const float*)d_in[6];
  const float* b_pw1_w  = (const float*)d_in[7];
  const float* b_pw1_b  = (const float*)d_in[8];
  const float* b_grn_g  = (const float*)d_in[9];
  const float* b_grn_b  = (const float*)d_in[10];
  const float* b_pw2_w  = (const float*)d_in[11];
  const float* b_pw2_b  = (const float*)d_in[12];
  const float* out_ln_w = (const float*)d_in[13];
  const float* out_ln_b = (const float*)d_in[14];
  const float* fc_rp_w  = (const float*)d_in[15];
  const float* fc_rp_b  = (const float*)d_in[16];
  const float* fc_gain_w= (const float*)d_in[17];
  const float* fc_gain_b= (const float*)d_in[18];
  const float* roll_in_w= (const float*)d_in[19];
  const float* roll_in_b= (const float*)d_in[20];
  const float* gru_wih  = (const float*)d_in[21];
  const float* gru_whh  = (const float*)d_in[22];
  const float* gru_bih  = (const float*)d_in[23];
  const float* gru_bhh  = (const float*)d_in[24];
  const float* roll_ln_w= (const float*)d_in[25];
  const float* roll_ln_b= (const float*)d_in[26];
  const float* fc_rp_r_w= (const float*)d_in[27];
  const float* fc_rp_r_b= (const float*)d_in[28];
  float* out = (float*)d_out;

  // ---- adaptive chunking ----
  // per-row floats: h(192) + yln(192) + mid(384; feats/y1, then rpraw(64)+rp(34)) = 768
  // fixed tail: scaleB 98304 + w_pad 12288 + b_pad 64 + xpost 8192 + hlast 49152
  //           + wT1 43008 + wPack 294912 = 505920 ; + margin
  const size_t SMAL_FLOATS = 505920 + 4096;
  size_t ws_floats = ws_size / 4;
  int nchunk = 256;
  const int cand[9] = {1,2,4,8,16,32,64,128,256};
  for (int ci=0; ci<9; ci++){
    size_t Mc_try = (size_t)M_ / cand[ci];
    if (Mc_try*768 + SMAL_FLOATS <= ws_floats){ nchunk = cand[ci]; break; }
  }
  const int    Bc = B_ / nchunk;
  const size_t Mc = (size_t)Bc * Q_;

  float* ws    = (float*)d_ws;
  float* h_c   = ws;
  float* yln_c = h_c   + Mc*192;
  float* mid_c = yln_c + Mc*192;
  float* smal  = mid_c + Mc*384;

  float* feats_c = mid_c;
  float* y1_c    = mid_c;
  float* rpraw   = mid_c;                // Mc*64 (y1 dead by then)
  float* rp_c    = mid_c + Mc*64;        // Mc*34

  float* scaleB = smal;                  // Bc*384 (reserve 98304)
  float* w_pad  = smal + 98304;          // 64*192
  float* b_pad  = w_pad + 12288;         // 64
  float* xpost  = b_pad + 64;            // B_*32
  float* hlast  = xpost + 8192;          // B_*192
  float* wT1    = hlast + 49152;         // 224*192
  float* wPack  = wT1 + 43008;           // 192*192*8

  // one-time weight prep
  pack_w_kernel<<<(64*192+255)/256, 256, 0, stream>>>(fc_rp_w, fc_rp_b, fc_gain_w, fc_gain_b, w_pad, b_pad);
  prep_rollout_kernel<<<(224*192+192*192+255)/256, 256, 0, stream>>>(roll_in_w, gru_wih, gru_whh, wT1, wPack);

  const int gmx = (int)(Mc/128);
  for (int ch=0; ch<nchunk; ch++){
    const float* x_c = x_in + (size_t)ch*Mc*D_;
    // 1. features + input projection
    feats_kernel<<<(int)((Mc*32+255)/256), 256, 0, stream>>>(x_c, feats_c, (int)Mc);
    gemm_t128<0><<<dim3(gmx, 3), 256, 0, stream>>>(feats_c, inp_w, inp_b,
                                                   h_c, nullptr, nullptr, H_, INCH_);
    // 2. ConvNeXt blocks
    for (int blk = 0; blk < 2; blk++){
      const float* dww = b_dw_w + blk*H_*9;     const float* dwb = b_dw_b + blk*H_;
      const float* lnw = b_ln_w + blk*H_;       const float* lnb = b_ln_b + blk*H_;
      const float* p1w = b_pw1_w + blk*HID_*H_; const float* p1b = b_pw1_b + blk*HID_;
      const float* gg  = b_grn_g + blk*HID_;    const float* gb  = b_grn_b + blk*HID_;
      const float* p2w = b_pw2_w + blk*H_*HID_; const float* p2b = b_pw2_b + blk*H_;
      dwconv_ln4<<<(int)(Mc/4), 192, 0, stream>>>(h_c, dww, dwb, lnw, lnb, yln_c);
      gemm_t128<1><<<dim3(gmx, 6), 256, 0, stream>>>(yln_c, p1w, p1b,
                                                     y1_c, nullptr, nullptr, HID_, H_);
      grn_stats_kernel<<<Bc, 384, 0, stream>>>(y1_c, gg, scaleB);
      gemm_t128<2><<<dim3(gmx, 3), 256, 0, stream>>>(y1_c, p2w, p2b,
                                                     h_c, scaleB, gb, H_, HID_);
    }
    // 3. output LN -> h_seq, save last-t rows
    out_ln_kernel<<<(int)Mc, 192, 0, stream>>>(h_c, out_ln_w, out_ln_b, yln_c, hlast, ch*Bc);
    // 4. Kalman projection + wide transcendental prep + FMA-only scan
    gemm_t128<0><<<dim3(gmx, 1), 256, 0, stream>>>(yln_c, w_pad, b_pad,
                                                   rpraw, nullptr, nullptr, 64, H_);
    kalman_prep_kernel<<<(int)((Mc*32+255)/256), 256, 0, stream>>>(rpraw, rp_c, (int)Mc);
    kalman_scan_kernel<<<(Bc+3)/4, 64, 0, stream>>>(x_c, rp_c, xpost, ch*Bc, Bc);
  }
  // 5. GRU rollout v3 (reverted): 128 blocks x 768 threads, BPB=2
  rollout_kernel<<<B_/BPB, RT_, 0, stream>>>(hlast, xpost, wT1, roll_in_b, wPack,
                                             gru_bih, gru_bhh, roll_ln_w, roll_ln_b,
                                             fc_rp_r_w, fc_rp_r_b, out);
  (void)in_sizes; (void)n_in; (void)out_size; (void)ws_size;
}

// Round 5
// 2522.044 us; speedup vs baseline: 1.6893x; 1.0322x over previous
//
#include <hip/hip_runtime.h>
#include <cstdint>
#include <cstddef>

#define B_    256
#define Q_    512
#define D_    32
#define H_    192
#define HID_  384
#define INCH_ 96
#define M_    (B_*Q_)    // 131072
#define WOUT_ 64
#define BPB   2          // batches per rollout block
#define RT_   768        // rollout threads: 4 quarters x 192, 12 waves
#define PI_F  3.14159265358979323846f

typedef unsigned int uint_t;

__device__ __forceinline__ float sigm(float x){ return 1.f/(1.f+expf(-x)); }
__device__ __forceinline__ float gelu_exact(float x){ return 0.5f*x*(1.f+erff(x*0.7071067811865475f)); }
__device__ __forceinline__ float4 f4sub(float4 a, float4 b){
  return make_float4(a.x-b.x, a.y-b.y, a.z-b.z, a.w-b.w);
}

// ---------------- on-the-fly features: [x, dy, ddy] column chunk (bit-identical to old feats_kernel) ----------------
__device__ __forceinline__ float4 feats_load(const float* __restrict__ x, int bt, int c){
  const int t = bt & 511;
  const int seg = c >> 5, d = c & 31;
  const float* xr = x + (size_t)bt*D_ + d;
  float4 x0 = *(const float4*)xr;
  if (seg == 0) return x0;
  if (t == 0) return make_float4(0.f,0.f,0.f,0.f);
  float4 x1 = *(const float4*)(xr - D_);
  float4 dy = f4sub(x0, x1);
  if (seg == 1) return dy;
  if (t == 1) return dy;                 // dym1 = 0 -> ddy = dy
  float4 x2 = *(const float4*)(xr - 2*D_);
  float4 dym1 = f4sub(x1, x2);
  return f4sub(dy, dym1);
}

// ---------------- 128x64x16 fp32 tiled GEMM, 4 blocks/CU, acc[8][4] ----------------
// MODE 0: out = acc+bias
// MODE 1: out = gelu(acc+bias), + per-block GRN column sum-of-squares partials -> gpart
// MODE 2: A affine (scale/grnb), C += acc+bias
// MODE 3: Kalman projection: write rp[m*34+..] = transforms(acc+bias) (N must be 64)
// K accumulation order is k-ascending per output element (bit-identical to BK=8 version).
template<int MODE>
__global__ __launch_bounds__(256,4) void gemm_t128(
    const float* __restrict__ Af,
    const float* __restrict__ W,  const float* __restrict__ bias,
    float* __restrict__ Cf,
    const float* __restrict__ scale, const float* __restrict__ grnb,
    float* __restrict__ gpart,
    int N, int K)
{
  __shared__ float As[16][128];
  __shared__ float Bs[16][64];
  __shared__ float red[16][64];
  const int tid = threadIdx.x;
  const int bm = blockIdx.x*128, bn = blockIdx.y*64;
  const int tx = tid & 15, ty = tid >> 4;
  const int arow = tid >> 1, ak = (tid & 1)*4;   // A: 128 rows x 2 threads, 2 chunks each
  const int brow = tid >> 2, bk = (tid & 3)*4;   // B: 64 rows x 4 threads
  const float* srow = (MODE==2) ? (scale + (size_t)(bm>>9)*HID_) : nullptr;

  float acc[8][4];
  #pragma unroll
  for (int i=0;i<8;i++)
    #pragma unroll
    for (int j=0;j<4;j++) acc[i][j]=0.f;

  const float* gA = Af + (size_t)(bm+arow)*K;
  const float* gB = W  + (size_t)(bn+brow)*K;

  for (int k0=0;k0<K;k0+=16){
    float4 va0 = *(const float4*)(gA + k0 + ak);
    float4 va1 = *(const float4*)(gA + k0 + ak + 8);
    float4 vb  = *(const float4*)(gB + k0 + bk);
    if (MODE==2){
      int c0 = k0+ak, c1 = k0+ak+8;
      float4 s0 = *(const float4*)(srow+c0);
      float4 g0 = *(const float4*)(grnb+c0);
      float4 s1 = *(const float4*)(srow+c1);
      float4 g1 = *(const float4*)(grnb+c1);
      va0.x = va0.x*s0.x+g0.x; va0.y = va0.y*s0.y+g0.y;
      va0.z = va0.z*s0.z+g0.z; va0.w = va0.w*s0.w+g0.w;
      va1.x = va1.x*s1.x+g1.x; va1.y = va1.y*s1.y+g1.y;
      va1.z = va1.z*s1.z+g1.z; va1.w = va1.w*s1.w+g1.w;
    }
    As[ak+0][arow]=va0.x; As[ak+1][arow]=va0.y; As[ak+2][arow]=va0.z; As[ak+3][arow]=va0.w;
    As[ak+8][arow]=va1.x; As[ak+9][arow]=va1.y; As[ak+10][arow]=va1.z; As[ak+11][arow]=va1.w;
    Bs[bk+0][brow]=vb.x; Bs[bk+1][brow]=vb.y; Bs[bk+2][brow]=vb.z; Bs[bk+3][brow]=vb.w;
    __syncthreads();
    #pragma unroll
    for (int kk=0;kk<16;kk++){
      float4 a0 = *(const float4*)&As[kk][ty*8];
      float4 a1 = *(const float4*)&As[kk][ty*8+4];
      float4 b  = *(const float4*)&Bs[kk][tx*4];
      float ar[8] = {a0.x,a0.y,a0.z,a0.w,a1.x,a1.y,a1.z,a1.w};
      #pragma unroll
      for (int i=0;i<8;i++){
        acc[i][0] += ar[i]*b.x; acc[i][1] += ar[i]*b.y;
        acc[i][2] += ar[i]*b.z; acc[i][3] += ar[i]*b.w;
      }
    }
    __syncthreads();
  }

  const int o0 = bn + tx*4;
  float4 b0 = *(const float4*)(bias + o0);

  if (MODE==3){
    // Kalman projection epilogue: rows write rp[m*34 + col] with transforms.
    #pragma unroll
    for (int i=0;i<8;i++){
      int m = bm + ty*8 + i;
      float* ob = Cf + (size_t)m*34;
      float vx = acc[i][0]+b0.x, vy = acc[i][1]+b0.y;
      float vz = acc[i][2]+b0.z, vw = acc[i][3]+b0.w;
      if (o0 == 0){
        float rho = 1.25f*sigm(vx);
        float phi = PI_F*tanhf(vy);
        ob[0] = rho*cosf(phi); ob[1] = rho*sinf(phi);
        ob[2] = sigm(vz); ob[3] = sigm(vw);
      } else if (o0 <= 28){
        ob[o0+0]=sigm(vx); ob[o0+1]=sigm(vy); ob[o0+2]=sigm(vz); ob[o0+3]=sigm(vw);
      } else if (o0 == 32){
        ob[32]=sigm(vx); ob[33]=sigm(vy);
      }
    }
    return;
  }

  float q0=0.f,q1=0.f,q2=0.f,q3=0.f;
  #pragma unroll
  for (int i=0;i<8;i++){
    int m = bm + ty*8 + i;
    if (MODE==0){
      float4 v; v.x=acc[i][0]+b0.x; v.y=acc[i][1]+b0.y; v.z=acc[i][2]+b0.z; v.w=acc[i][3]+b0.w;
      *(float4*)(Cf + (size_t)m*N + o0) = v;
    } else if (MODE==1){
      float4 v;
      v.x = gelu_exact(acc[i][0]+b0.x); v.y = gelu_exact(acc[i][1]+b0.y);
      v.z = gelu_exact(acc[i][2]+b0.z); v.w = gelu_exact(acc[i][3]+b0.w);
      *(float4*)(Cf + (size_t)m*N + o0) = v;
      q0 += v.x*v.x; q1 += v.y*v.y; q2 += v.z*v.z; q3 += v.w*v.w;
    } else {
      float4 old = *(const float4*)(Cf + (size_t)m*N + o0);
      float4 v; v.x=old.x+acc[i][0]+b0.x; v.y=old.y+acc[i][1]+b0.y;
      v.z=old.z+acc[i][2]+b0.z; v.w=old.w+acc[i][3]+b0.w;
      *(float4*)(Cf + (size_t)m*N + o0) = v;
    }
  }

  if (MODE==1){
    // per-block GRN partials: sum v^2 over this block's 128 rows for each of 64 cols
    red[ty][tx*4+0]=q0; red[ty][tx*4+1]=q1; red[ty][tx*4+2]=q2; red[ty][tx*4+3]=q3;
    __syncthreads();
    if (tid < 64){
      float s = 0.f;
      #pragma unroll
      for (int t=0;t<16;t++) s += red[t][tid];
      const int slot = (bm>>7)&3, b = bm>>9;
      gpart[((size_t)(b*4+slot))*HID_ + bn + tid] = s;
    }
  }
}

// ---------------- input GEMM with fused feature synthesis (replaces feats_kernel + inp gemm) ----------------
__global__ __launch_bounds__(256,4) void gemm_inp(
    const float* __restrict__ x,
    const float* __restrict__ W,  const float* __restrict__ bias,
    float* __restrict__ Cf, int N, int K)
{
  __shared__ float As[16][128];
  __shared__ float Bs[16][64];
  const int tid = threadIdx.x;
  const int bm = blockIdx.x*128, bn = blockIdx.y*64;
  const int tx = tid & 15, ty = tid >> 4;
  const int arow = tid >> 1, ak = (tid & 1)*4;
  const int brow = tid >> 2, bk = (tid & 3)*4;

  float acc[8][4];
  #pragma unroll
  for (int i=0;i<8;i++)
    #pragma unroll
    for (int j=0;j<4;j++) acc[i][j]=0.f;

  const float* gB = W + (size_t)(bn+brow)*K;

  for (int k0=0;k0<K;k0+=16){
    float4 va0 = feats_load(x, bm+arow, k0+ak);
    float4 va1 = feats_load(x, bm+arow, k0+ak+8);
    float4 vb  = *(const float4*)(gB + k0 + bk);
    As[ak+0][arow]=va0.x; As[ak+1][arow]=va0.y; As[ak+2][arow]=va0.z; As[ak+3][arow]=va0.w;
    As[ak+8][arow]=va1.x; As[ak+9][arow]=va1.y; As[ak+10][arow]=va1.z; As[ak+11][arow]=va1.w;
    Bs[bk+0][brow]=vb.x; Bs[bk+1][brow]=vb.y; Bs[bk+2][brow]=vb.z; Bs[bk+3][brow]=vb.w;
    __syncthreads();
    #pragma unroll
    for (int kk=0;kk<16;kk++){
      float4 a0 = *(const float4*)&As[kk][ty*8];
      float4 a1 = *(const float4*)&As[kk][ty*8+4];
      float4 b  = *(const float4*)&Bs[kk][tx*4];
      float ar[8] = {a0.x,a0.y,a0.z,a0.w,a1.x,a1.y,a1.z,a1.w};
      #pragma unroll
      for (int i=0;i<8;i++){
        acc[i][0] += ar[i]*b.x; acc[i][1] += ar[i]*b.y;
        acc[i][2] += ar[i]*b.z; acc[i][3] += ar[i]*b.w;
      }
    }
    __syncthreads();
  }

  const int o0 = bn + tx*4;
  float4 b0 = *(const float4*)(bias + o0);
  #pragma unroll
  for (int i=0;i<8;i++){
    int m = bm + ty*8 + i;
    float4 v; v.x=acc[i][0]+b0.x; v.y=acc[i][1]+b0.y; v.z=acc[i][2]+b0.z; v.w=acc[i][3]+b0.w;
    *(float4*)(Cf + (size_t)m*N + o0) = v;
  }
}

// ---------------- depthwise conv (k=9, edge pad) + LN, 16 timesteps per block ----------------
__global__ __launch_bounds__(192) void dwconv_ln16(
  const float* __restrict__ h, const float* __restrict__ dww, const float* __restrict__ dwb,
  const float* __restrict__ lnw, const float* __restrict__ lnb, float* __restrict__ yln)
{
  __shared__ float sh[24][192];
  __shared__ float rs_[192], rq_[192], st[2];
  const int c  = threadIdx.x;
  const int t0 = (blockIdx.x & 31) * 16;
  const size_t base = (size_t)(blockIdx.x >> 5) * Q_ * H_;
  #pragma unroll
  for (int r=0;r<24;r++){
    int tt = t0 - 4 + r; tt = tt<0?0:(tt>511?511:tt);
    sh[r][c] = h[base + (size_t)tt*H_ + c];
  }
  float w[9];
  #pragma unroll
  for (int k=0;k<9;k++) w[k] = dww[c*9+k];
  const float dbias = dwb[c], lw = lnw[c], lb = lnb[c];
  __syncthreads();
  for (int i=0;i<16;i++){
    float acc = dbias;
    #pragma unroll
    for (int k=0;k<9;k++) acc += w[k]*sh[i+k][c];
    rs_[c]=acc; rq_[c]=acc*acc;
    __syncthreads();
    if (c < 64){
      float s = rs_[c]+rs_[c+64]+rs_[c+128];
      float q = rq_[c]+rq_[c+64]+rq_[c+128];
      #pragma unroll
      for (int off=32; off>0; off>>=1){ s += __shfl_down(s,off); q += __shfl_down(q,off); }
      if (c==0){ st[0]=s; st[1]=q; }
    }
    __syncthreads();
    float mean = st[0]*(1.f/H_);
    float var  = st[1]*(1.f/H_) - mean*mean;
    float r = rsqrtf(var + 1e-5f);
    yln[base + (size_t)(t0+i)*H_ + c] = (acc-mean)*r*lw + lb;
  }
}

// ---------------- output LayerNorm (+ save last-timestep row) ----------------
__global__ __launch_bounds__(192) void out_ln_kernel(
  const float* __restrict__ h, const float* __restrict__ lnw, const float* __restrict__ lnb,
  float* __restrict__ o, float* __restrict__ hlast, int b0)
{
  __shared__ float rs_[192], rq_[192], st[2];
  const int c  = threadIdx.x;
  const int bt = blockIdx.x;
  float v = h[(size_t)bt*H_ + c];
  rs_[c]=v; rq_[c]=v*v;
  __syncthreads();
  if (c < 64){
    float s = rs_[c]+rs_[c+64]+rs_[c+128];
    float q = rq_[c]+rq_[c+64]+rq_[c+128];
    #pragma unroll
    for (int off=32; off>0; off>>=1){ s += __shfl_down(s,off); q += __shfl_down(q,off); }
    if (c==0){ st[0]=s; st[1]=q; }
  }
  __syncthreads();
  float mean = st[0]*(1.f/H_);
  float var  = st[1]*(1.f/H_) - mean*mean;
  float r = rsqrtf(var + 1e-5f);
  float res = (v-mean)*r*lnw[c] + lnb[c];
  o[(size_t)bt*H_ + c] = res;
  if ((bt & 511) == 511) hlast[(size_t)(b0 + (bt>>9))*H_ + c] = res;
}

// ---------------- GRN combine: 4 slot partials -> scale (reads 1.5 MB instead of 201 MB) ----------------
__global__ __launch_bounds__(384) void grn_combine_kernel(
  const float* __restrict__ gpart, const float* __restrict__ grn_g, float* __restrict__ scale)
{
  __shared__ float r[384];
  const int c = threadIdx.x;
  const int b = blockIdx.x;
  const float* p = gpart + (size_t)b*4*HID_;
  float s = ((p[c] + p[HID_+c]) + p[2*HID_+c]) + p[3*HID_+c];
  float gx = sqrtf(s);
  r[c] = gx;
  __syncthreads();
  if (c < 64){
    float v = r[c]+r[c+64]+r[c+128]+r[c+192]+r[c+256]+r[c+320];
    #pragma unroll
    for (int off=32; off>0; off>>=1) v += __shfl_down(v,off);
    if (c==0) r[0]=v;
  }
  __syncthreads();
  float mean = r[0]*(1.f/HID_);
  scale[(size_t)b*HID_ + c] = 1.f + grn_g[c]*gx/(mean + 1e-6f);
}

// ---------------- pack fc_rp / fc_gain into padded (64,192) W ----------------
__global__ void pack_w_kernel(const float* __restrict__ frw, const float* __restrict__ frb,
                              const float* __restrict__ fgw, const float* __restrict__ fgb,
                              float* __restrict__ w_pad, float* __restrict__ b_pad)
{
  int idx = blockIdx.x*256 + threadIdx.x;
  if (idx >= 64*192) return;
  int o = idx / 192, k = idx % 192;
  float v = 0.f;
  if (o < 2) v = frw[o*192+k]; else if (o < 34) v = fgw[(o-2)*192+k];
  w_pad[idx] = v;
  if (k == 0){
    float bv = 0.f;
    if (o < 2) bv = frb[o]; else if (o < 34) bv = fgb[o-2];
    b_pad[o] = bv;
  }
}

// ---------------- sequential Kalman scan (FMA-only) ----------------
__global__ __launch_bounds__(64) void kalman_scan_kernel(
  const float* __restrict__ x_c, const float* __restrict__ rp, float* __restrict__ xpost,
  int b0, int Bc)
{
  const int lane = threadIdx.x;
  const int bl = blockIdx.x*4 + (lane>>4);
  if (bl >= Bc) return;
  const int m = lane & 15;
  const float* xb  = x_c + (size_t)bl*Q_*D_;
  const float* rpb = rp  + (size_t)bl*Q_*34;
  float re = xb[m], im = xb[16+m];
  for (int t=0;t<Q_;t++){
    const float* r = rpb + (size_t)t*34;
    float rc = r[0], rs = r[1];
    float g0 = r[2+m], g1 = r[18+m];
    float y0 = xb[(size_t)t*D_ + m], y1v = xb[(size_t)t*D_ + 16 + m];
    float pr  = rc*re - rs*im;
    float pim = rs*re + rc*im;
    re = pr  + g0*(y0  - pr);
    im = pim + g1*(y1v - pim);
  }
  xpost[(b0+bl)*D_ + m] = re;
  xpost[(b0+bl)*D_ + 16 + m] = im;
}

// ---------------- rollout weight prep: wT1[k][o] + packed [k][o][8] gate block ----------------
__global__ void prep_rollout_kernel(const float* __restrict__ riw, const float* __restrict__ wih,
                                    const float* __restrict__ whh,
                                    float* __restrict__ wT1, float* __restrict__ wPack)
{
  int idx = blockIdx.x*256 + threadIdx.x;
  if (idx < 224*192){
    int o = idx % 192, k = idx / 192;
    wT1[idx] = riw[o*224 + k];
    return;
  }
  idx -= 224*192;
  if (idx < 192*192){
    int o = idx % 192, k = idx / 192;
    float* w = wPack + ((size_t)k*192 + o)*8;
    w[0] = wih[(0*192+o)*192 + k];
    w[1] = wih[(1*192+o)*192 + k];
    w[2] = wih[(2*192+o)*192 + k];
    w[3] = whh[(0*192+o)*192 + k];
    w[4] = whh[(1*192+o)*192 + k];
    w[5] = whh[(2*192+o)*192 + k];
    w[6] = 0.f; w[7] = 0.f;
  }
}

// ---------------- GRU rollout v3 (proven 890us): BPB=2, 128 blocks ----------------
// - wT1 (phase-A weights) live in 56 registers per thread, loaded once (step-invariant).
//   NOTE: phase-B weights stay as L2 streams; promoting them (288 floats) exceeds SROA's
//   limit and spills to scratch (R3: 3.5 GB scratch traffic, 2.3 ms). Do not retry.
// - Single fused reduction per step; LN-update and Kalman-rotate run concurrently.
__global__ __launch_bounds__(RT_,3) void rollout_kernel(
  const float* __restrict__ hlast, const float* __restrict__ xpost,
  const float* __restrict__ wT1,  const float* __restrict__ rib_,
  const float* __restrict__ wPack,
  const float* __restrict__ bih,  const float* __restrict__ bhh,
  const float* __restrict__ lnw,  const float* __restrict__ lnb,
  const float* __restrict__ frw,  const float* __restrict__ frb,
  float* __restrict__ out)
{
  const int tid = threadIdx.x;
  const int q   = tid / 192;        // quarter 0..3 (wave-aligned: 192 = 3 waves)
  const int o   = tid - q*192;      // channel 0..191
  const int bb  = blockIdx.x*BPB;

  __shared__ float hT[192][2];      // h state, batch-major
  __shared__ float xT[192][2];      // x = tanh(W1 [h;c]), batch-major
  __shared__ float cT[32][2];       // curr (Kalman state), batch-major
  __shared__ float pA[4][2][192];   // phase-A partials [quarter][batch][o]
  __shared__ float pB[4][12][192];  // phase-B partials [quarter][batch*6+gate][o]
  __shared__ float rsum[2][3][4];   // [batch][wave][S1,S2,S3,S4]

  // ---- init state ----
  if (q < 2){
    hT[o][q] = hlast[(size_t)(bb+q)*H_ + o];
    if (o < 32) cT[o][q] = xpost[(bb+q)*D_ + o];
  }

  const float w_ln = lnw[o], b_ln = lnb[o];
  const float fr0  = frw[o], fr1  = frw[192+o];
  const float fb0 = frb[0],  fb1 = frb[1];
  const float bi0 = bih[o], bi1 = bih[192+o], bi2 = bih[384+o];
  const float bh0 = bhh[o], bh1 = bhh[192+o], bh2 = bhh[384+o];
  const float rib = rib_[o];
  const float u0 = w_ln*fr0, u1 = w_ln*fr1;      // for fused projection
  const float t0c = b_ln*fr0, t1c = b_ln*fr1;

  // ---- phase-A weights in registers (step-invariant) ----
  float wreg[56];
  if (q < 3){
    const int kb = 56*q;
    #pragma unroll
    for (int i=0;i<56;i++) wreg[i] = wT1[(kb+i)*192+o];
  } else {
    #pragma unroll
    for (int i=0;i<24;i++) wreg[i] = wT1[(168+i)*192+o];
    #pragma unroll
    for (int i=0;i<32;i++) wreg[24+i] = wT1[(192+i)*192+o];
  }

  // ---- one-time constants: C0=sum(u0), C1=sum(u1), K0=sum(lnb*fr0)+fb0, K1=sum(lnb*fr1)+fb1 ----
  {
    float c0=u0, c1=u1, k0=t0c, k1=t1c;
    #pragma unroll
    for (int off=32; off>0; off>>=1){
      c0 += __shfl_down(c0,off); c1 += __shfl_down(c1,off);
      k0 += __shfl_down(k0,off); k1 += __shfl_down(k1,off);
    }
    if (q==0 && (o&63)==0){
      int w = o>>6;
      rsum[0][w][0]=c0; rsum[0][w][1]=c1; rsum[0][w][2]=k0; rsum[0][w][3]=k1;
    }
  }
  __syncthreads();
  const float C0 = rsum[0][0][0]+rsum[0][1][0]+rsum[0][2][0];
  const float C1 = rsum[0][0][1]+rsum[0][1][1]+rsum[0][2][1];
  const float K0 = rsum[0][0][2]+rsum[0][1][2]+rsum[0][2][2] + fb0;
  const float K1 = rsum[0][0][3]+rsum[0][1][3]+rsum[0][2][3] + fb1;

  for (int s=0; s<WOUT_; s++){
    // ---- phase A: partial x = W1 @ [h;c], K=224 split 4-way, weights in regs ----
    float a0=0.f, a1=0.f;
    if (q < 3){
      const int kb = 56*q;
      #pragma unroll
      for (int i=0;i<56;i++){
        float2 h2 = *(const float2*)&hT[kb+i][0];
        a0 += wreg[i]*h2.x; a1 += wreg[i]*h2.y;
      }
    } else {
      #pragma unroll
      for (int i=0;i<24;i++){
        float2 h2 = *(const float2*)&hT[168+i][0];
        a0 += wreg[i]*h2.x; a1 += wreg[i]*h2.y;
      }
      #pragma unroll
      for (int i=0;i<32;i++){
        float2 c2 = *(const float2*)&cT[i][0];
        a0 += wreg[24+i]*c2.x; a1 += wreg[24+i]*c2.y;
      }
    }
    pA[q][0][o]=a0; pA[q][1][o]=a1;
    __syncthreads();

    // ---- x combine: quarter j (<2) owns batch j ----
    if (q < 2){
      xT[o][q] = tanhf(rib + pA[0][q][o] + pA[1][q][o] + pA[2][q][o] + pA[3][q][o]);
    }
    __syncthreads();

    // ---- phase B: partial gates, K=192 split 4-way (48 each) ----
    float accx[2][3] = {{0.f,0.f,0.f},{0.f,0.f,0.f}};
    float acch[2][3] = {{0.f,0.f,0.f},{0.f,0.f,0.f}};
    {
      const int kb2 = 48*q;
      #pragma unroll 4
      for (int i=0;i<48;i++){
        const int k = kb2+i;
        const float4* wp = (const float4*)(wPack + ((size_t)k*192 + o)*8);
        const float4 wA = wp[0];
        const float4 wB = wp[1];
        const float2 xx = *(const float2*)&xT[k][0];
        const float2 hh = *(const float2*)&hT[k][0];
        accx[0][0] += wA.x*xx.x; accx[0][1] += wA.y*xx.x; accx[0][2] += wA.z*xx.x;
        accx[1][0] += wA.x*xx.y; accx[1][1] += wA.y*xx.y; accx[1][2] += wA.z*xx.y;
        acch[0][0] += wA.w*hh.x; acch[0][1] += wB.x*hh.x; acch[0][2] += wB.y*hh.x;
        acch[1][0] += wA.w*hh.y; acch[1][1] += wB.x*hh.y; acch[1][2] += wB.y*hh.y;
      }
    }
    #pragma unroll
    for (int j=0;j<2;j++){
      #pragma unroll
      for (int g=0;g<3;g++){
        pB[q][j*6+g][o]   = accx[j][g];
        pB[q][j*6+3+g][o] = acch[j][g];
      }
    }
    __syncthreads();

    // ---- gate combine + fused 4-sum wave reduction (quarters 0/1 own batch q) ----
    float pre = 0.f;
    if (q < 2){
      const int g6 = q*6;
      float P0 = bi0 + pB[0][g6+0][o]+pB[1][g6+0][o]+pB[2][g6+0][o]+pB[3][g6+0][o];
      float P1 = bi1 + pB[0][g6+1][o]+pB[1][g6+1][o]+pB[2][g6+1][o]+pB[3][g6+1][o];
      float P2 = bi2 + pB[0][g6+2][o]+pB[1][g6+2][o]+pB[2][g6+2][o]+pB[3][g6+2][o];
      float Q0 = bh0 + pB[0][g6+3][o]+pB[1][g6+3][o]+pB[2][g6+3][o]+pB[3][g6+3][o];
      float Q1 = bh1 + pB[0][g6+4][o]+pB[1][g6+4][o]+pB[2][g6+4][o]+pB[3][g6+4][o];
      float Q2 = bh2 + pB[0][g6+5][o]+pB[1][g6+5][o]+pB[2][g6+5][o]+pB[3][g6+5][o];
      float rg = sigm(P0+Q0), zz = sigm(P1+Q1);
      float nn = tanhf(P2 + rg*Q2);
      pre = (1.f-zz)*nn + zz*hT[o][q];
      float s1 = pre, s2 = pre*pre, s3 = pre*u0, s4 = pre*u1;
      #pragma unroll
      for (int off=32; off>0; off>>=1){
        s1 += __shfl_down(s1,off); s2 += __shfl_down(s2,off);
        s3 += __shfl_down(s3,off); s4 += __shfl_down(s4,off);
      }
      if ((o&63)==0){
        int w = o>>6;
        rsum[q][w][0]=s1; rsum[q][w][1]=s2; rsum[q][w][2]=s3; rsum[q][w][3]=s4;
      }
    }
    __syncthreads();

    // ---- concurrent tail: LN update (q<2) || Kalman rotate (q>=2, o<16) ----
    if (q < 2){
      float S1 = rsum[q][0][0]+rsum[q][1][0]+rsum[q][2][0];
      float S2 = rsum[q][0][1]+rsum[q][1][1]+rsum[q][2][1];
      float mu  = S1*(1.f/192.f);
      float var = S2*(1.f/192.f) - mu*mu;
      float r = rsqrtf(var+1e-5f);
      hT[o][q] = (pre-mu)*r*w_ln + b_ln;
    } else if (o < 16){
      const int j = q-2;
      float S1 = rsum[j][0][0]+rsum[j][1][0]+rsum[j][2][0];
      float S2 = rsum[j][0][1]+rsum[j][1][1]+rsum[j][2][1];
      float S3 = rsum[j][0][2]+rsum[j][1][2]+rsum[j][2][2];
      float S4 = rsum[j][0][3]+rsum[j][1][3]+rsum[j][2][3];
      float mu  = S1*(1.f/192.f);
      float var = S2*(1.f/192.f) - mu*mu;
      float r = rsqrtf(var+1e-5f);
      float proj0 = r*(S3 - mu*C0) + K0;
      float proj1 = r*(S4 - mu*C1) + K1;
      float rho = 1.25f*sigm(proj0);
      float phi = PI_F*tanhf(proj1);
      float rc = rho*cosf(phi), rs = rho*sinf(phi);
      float re = cT[o][j], im = cT[o+16][j];
      float nre = rc*re - rs*im;
      float nim = rs*re + rc*im;
      cT[o][j] = nre; cT[o+16][j] = nim;
      float* ob = out + ((size_t)(bb+j)*WOUT_ + s)*D_;
      ob[o] = nre; ob[o+16] = nim;
    }
    __syncthreads();
  }
}

// ---------------- host launch ----------------
extern "C" void kernel_launch(void* const* d_in, const int* in_sizes, int n_in,
                              void* d_out, int out_size, void* d_ws, size_t ws_size,
                              hipStream_t stream)
{
  const float* x_in     = (const float*)d_in[0];
  const float* inp_w    = (const float*)d_in[1];
  const float* inp_b    = (const float*)d_in[2];
  const float* b_dw_w   = (const float*)d_in[3];
  const float* b_dw_b   = (const float*)d_in[4];
  const float* b_ln_w   = (const float*)d_in[5];
  const float* b_ln_b   = (const float*)d_in[6];
  const float* b_pw1_w  = (const float*)d_in[7];
  const float* b_pw1_b  = (const float*)d_in[8];
  const float* b_grn_g  = (const float*)d_in[9];
  const float* b_grn_b  = (const float*)d_in[10];
  const float* b_pw2_w  = (const float*)d_in[11];
  const float* b_pw2_b  = (const float*)d_in[12];
  const float* out_ln_w = (const float*)d_in[13];
  const float* out_ln_b = (const float*)d_in[14];
  const float* fc_rp_w  = (const float*)d_in[15];
  const float* fc_rp_b  = (const float*)d_in[16];
  const float* fc_gain_w= (const float*)d_in[17];
  const float* fc_gain_b= (const float*)d_in[18];
  const float* roll_in_w= (const float*)d_in[19];
  const float* roll_in_b= (const float*)d_in[20];
  const float* gru_wih  = (const float*)d_in[21];
  const float* gru_whh  = (const float*)d_in[22];
  const float* gru_bih  = (const float*)d_in[23];
  const float* gru_bhh  = (const float*)d_in[24];
  const float* roll_ln_w= (const float*)d_in[25];
  const float* roll_ln_b= (const float*)d_in[26];
  const float* fc_rp_r_w= (const float*)d_in[27];
  const float* fc_rp_r_b= (const float*)d_in[28];
  float* out = (float*)d_out;

  // ---- adaptive chunking ----
  // per-row floats: h(192) + yln(192) + mid(384; y1, later rp(34)) = 768
  // fixed tail: scaleB 98304 + w_pad 12288 + b_pad 64 + xpost 8192 + hlast 49152
  //           + wT1 43008 + wPack 294912 + gpart 393216 = 899136 ; + margin
  const size_t SMAL_FLOATS = 899136 + 4096;
  size_t ws_floats = ws_size / 4;
  int nchunk = 256;
  const int cand[9] = {1,2,4,8,16,32,64,128,256};
  for (int ci=0; ci<9; ci++){
    size_t Mc_try = (size_t)M_ / cand[ci];
    if (Mc_try*768 + SMAL_FLOATS <= ws_floats){ nchunk = cand[ci]; break; }
  }
  const int    Bc = B_ / nchunk;
  const size_t Mc = (size_t)Bc * Q_;

  float* ws    = (float*)d_ws;
  float* h_c   = ws;
  float* yln_c = h_c   + Mc*192;
  float* mid_c = yln_c + Mc*192;
  float* smal  = mid_c + Mc*384;

  float* y1_c    = mid_c;
  float* rp_c    = mid_c;                // Mc*34 (y1 dead by then)

  float* scaleB = smal;                  // Bc*384 (reserve 98304)
  float* w_pad  = smal + 98304;          // 64*192
  float* b_pad  = w_pad + 12288;         // 64
  float* xpost  = b_pad + 64;            // B_*32
  float* hlast  = xpost + 8192;          // B_*192
  float* wT1    = hlast + 49152;         // 224*192
  float* wPack  = wT1 + 43008;           // 192*192*8
  float* gpart  = wPack + 294912;        // 4*Bc*384 (reserve 393216)

  // one-time weight prep
  pack_w_kernel<<<(64*192+255)/256, 256, 0, stream>>>(fc_rp_w, fc_rp_b, fc_gain_w, fc_gain_b, w_pad, b_pad);
  prep_rollout_kernel<<<(224*192+192*192+255)/256, 256, 0, stream>>>(roll_in_w, gru_wih, gru_whh, wT1, wPack);

  const int gmx = (int)(Mc/128);
  for (int ch=0; ch<nchunk; ch++){
    const float* x_c = x_in + (size_t)ch*Mc*D_;
    // 1. fused features + input projection
    gemm_inp<<<dim3(gmx, 3), 256, 0, stream>>>(x_c, inp_w, inp_b, h_c, H_, INCH_);
    // 2. ConvNeXt blocks
    for (int blk = 0; blk < 2; blk++){
      const float* dww = b_dw_w + blk*H_*9;     const float* dwb = b_dw_b + blk*H_;
      const float* lnw = b_ln_w + blk*H_;       const float* lnb = b_ln_b + blk*H_;
      const float* p1w = b_pw1_w + blk*HID_*H_; const float* p1b = b_pw1_b + blk*HID_;
      const float* gg  = b_grn_g + blk*HID_;    const float* gb  = b_grn_b + blk*HID_;
      const float* p2w = b_pw2_w + blk*H_*HID_; const float* p2b = b_pw2_b + blk*H_;
      dwconv_ln16<<<(int)(Mc/16), 192, 0, stream>>>(h_c, dww, dwb, lnw, lnb, yln_c);
      gemm_t128<1><<<dim3(gmx, 6), 256, 0, stream>>>(yln_c, p1w, p1b,
                                                     y1_c, nullptr, nullptr, gpart, HID_, H_);
      grn_combine_kernel<<<Bc, 384, 0, stream>>>(gpart, gg, scaleB);
      gemm_t128<2><<<dim3(gmx, 3), 256, 0, stream>>>(y1_c, p2w, p2b,
                                                     h_c, scaleB, gb, nullptr, H_, HID_);
    }
    // 3. output LN -> h_seq, save last-t rows
    out_ln_kernel<<<(int)Mc, 192, 0, stream>>>(h_c, out_ln_w, out_ln_b, yln_c, hlast, ch*Bc);
    // 4. fused Kalman projection GEMM (writes rp directly) + FMA-only scan
    gemm_t128<3><<<dim3(gmx, 1), 256, 0, stream>>>(yln_c, w_pad, b_pad,
                                                   rp_c, nullptr, nullptr, nullptr, 64, H_);
    kalman_scan_kernel<<<(Bc+3)/4, 64, 0, stream>>>(x_c, rp_c, xpost, ch*Bc, Bc);
  }
  // 5. GRU rollout v3 (proven): 128 blocks x 768 threads, BPB=2
  rollout_kernel<<<B_/BPB, RT_, 0, stream>>>(hlast, xpost, wT1, roll_in_b, wPack,
                                             gru_bih, gru_bhh, roll_ln_w, roll_ln_b,
                                             fc_rp_r_w, fc_rp_r_b, out);
  (void)in_sizes; (void)n_in; (void)out_size; (void)ws_size;
}